// Round 1
// 595.286 us; speedup vs baseline: 1.2028x; 1.2028x over previous
//
#include <hip/hip_runtime.h>

#define NN 4096
#define NSTEPS 100
#define TPB 512
#define NBLK 256     // 1 block per CU; 16 rows per block, K pinned in VGPRs

// Coherent (cross-XCD) 8-byte load/store: relaxed agent-scope atomics compile
// to sc-flagged global ops that bypass the non-coherent L1/L2 and hit the
// coherence point directly — WITHOUT the buffer_wbl2 / buffer_inv cache
// maintenance that release/acquire fences emit (the R1 killer).
__device__ __forceinline__ void zstore_u64(float2* p, unsigned long long u) {
    __hip_atomic_store((unsigned long long*)p, u, __ATOMIC_RELAXED,
                       __HIP_MEMORY_SCOPE_AGENT);
}
__device__ __forceinline__ unsigned long long zload_u64(const float2* p) {
    return __hip_atomic_load((const unsigned long long*)p, __ATOMIC_RELAXED,
                             __HIP_MEMORY_SCOPE_AGENT);
}

// Barrier-free persistent kernel. z_g (g>=1) lives in zb[g&1]; each element's
// x-mantissa low 3 bits carry tag = g&7. Stale content in zb[g&1] is z_{g-2}
// (tag differs by 2 mod 8) or memset-0 (tag 0, first writes have tag 1/2) —
// always distinguishable. Producers publish with ONE relaxed store (no fence,
// no waitcnt, no flag); consumers poll the data itself until tags match.
//
// R2 change: BATCHED re-poll. The old per-element `while` validated elements
// in order and re-issued only the element being waited on — when the whole
// initial batch was stale (the common case: consumers race ahead of the
// publish), elements 1..7 each paid a full serial coherence-point round trip
// (~8 x ~1.5k cy ~= 5 us/step, the dominant cost per the counter model).
// Now: build a stale mask, re-issue ALL stale loads together each round.
__global__ __launch_bounds__(TPB, 2) void k_persist(
    const float* __restrict__ K, const float2* __restrict__ z0,
    float2* __restrict__ zb0, float2* __restrict__ zb1,
    float2* __restrict__ zfinal, const float* __restrict__ omega_p,
    const float* __restrict__ dt_p) {
    __shared__ float zr[NN];
    __shared__ float zi[NN];
    __shared__ float P[8][8];

    const int tid  = threadIdx.x;
    const int bid  = blockIdx.x;
    const int w    = tid >> 6, lane = tid & 63;
    const int g    = w >> 1,   h    = w & 1;
    const int rb   = bid * 16 + g * 4;          // first of this wave's 4 rows
    const int cb   = h * 2048 + lane * 4;       // lane's col base (j stride 256)

    const float omega = *omega_p;
    const float dt    = *dt_p;
    const float inv2n = 1.0f / (2.0f * NN);

    // ---- load K fragment: 4 rows x 8 float4 = 128 VGPRs ----
    float4 kA[4][8];
#pragma unroll
    for (int r = 0; r < 4; ++r) {
        const float* Kr = K + (size_t)(rb + r) * NN + cb;
#pragma unroll
        for (int j = 0; j < 8; ++j) kA[r][j] = *(const float4*)(Kr + j * 256);
    }

    for (int s = 0; s < NSTEPS; ++s) {
        // Pin kA in registers: opaque redefinition each iteration so the
        // compiler can neither spill-and-reload nor refold the global loads.
#pragma unroll
        for (int r = 0; r < 4; ++r)
#pragma unroll
            for (int j = 0; j < 8; ++j)
                asm volatile("" : "+v"(kA[r][j].x), "+v"(kA[r][j].y),
                                  "+v"(kA[r][j].z), "+v"(kA[r][j].w));

        // ---- stage z_s -> LDS (SoA), conflict-free ----
        if (s == 0) {
#pragma unroll
            for (int it = 0; it < 8; ++it) {
                int idx = it * TPB + tid;
                float2 v = z0[idx];
                zr[idx] = v.x; zi[idx] = v.y;
            }
        } else {
            const float2* zsrc = (s & 1) ? zb1 : zb0;
            const unsigned tag = (unsigned)(s & 7);
            const int rot = bid & 7;             // spread chunk demand
            int idx[8];
            unsigned long long v[8];
#pragma unroll
            for (int it = 0; it < 8; ++it) {     // 8 loads in flight
                idx[it] = ((it + rot) & 7) * TPB + tid;
                v[it] = zload_u64(zsrc + idx[it]);
            }
            // Batched re-poll: one coherence round trip per ROUND, not per
            // stale element.
            unsigned stale = 0u;
#pragma unroll
            for (int it = 0; it < 8; ++it)
                stale |= (((unsigned)v[it] & 7u) != tag) ? (1u << it) : 0u;
            while (stale) {
                __builtin_amdgcn_s_sleep(1);
#pragma unroll
                for (int it = 0; it < 8; ++it)   // re-issue ALL stale together
                    if (stale & (1u << it)) v[it] = zload_u64(zsrc + idx[it]);
#pragma unroll
                for (int it = 0; it < 8; ++it)
                    if ((stale & (1u << it)) &&
                        ((unsigned)v[it] & 7u) == tag)
                        stale &= ~(1u << it);
            }
#pragma unroll
            for (int it = 0; it < 8; ++it) {
                union { unsigned u; float f; } cx, cy;
                cx.u = (unsigned)v[it];
                cy.u = (unsigned)(v[it] >> 32);
                zr[idx[it]] = cx.f; zi[idx[it]] = cy.f;
            }
        }
        __syncthreads();

        // ---- dots: 4 rows x 2048 cols per wave, K from regs, z from LDS ----
        float sr0 = 0, sr1 = 0, sr2 = 0, sr3 = 0;
        float si0 = 0, si1 = 0, si2 = 0, si3 = 0;
#pragma unroll
        for (int j = 0; j < 8; ++j) {
            float4 a = *(const float4*)&zr[cb + j * 256];
            float4 b = *(const float4*)&zi[cb + j * 256];
            float4 k0 = kA[0][j], k1 = kA[1][j], k2 = kA[2][j], k3 = kA[3][j];
            sr0 += k0.x * a.x + k0.y * a.y + k0.z * a.z + k0.w * a.w;
            si0 += k0.x * b.x + k0.y * b.y + k0.z * b.z + k0.w * b.w;
            sr1 += k1.x * a.x + k1.y * a.y + k1.z * a.z + k1.w * a.w;
            si1 += k1.x * b.x + k1.y * b.y + k1.z * b.z + k1.w * b.w;
            sr2 += k2.x * a.x + k2.y * a.y + k2.z * a.z + k2.w * a.w;
            si2 += k2.x * b.x + k2.y * b.y + k2.z * b.z + k2.w * b.w;
            sr3 += k3.x * a.x + k3.y * a.y + k3.z * a.z + k3.w * a.w;
            si3 += k3.x * b.x + k3.y * b.y + k3.z * b.z + k3.w * b.w;
        }
#pragma unroll
        for (int off = 32; off; off >>= 1) {
            sr0 += __shfl_xor(sr0, off, 64); si0 += __shfl_xor(si0, off, 64);
            sr1 += __shfl_xor(sr1, off, 64); si1 += __shfl_xor(si1, off, 64);
            sr2 += __shfl_xor(sr2, off, 64); si2 += __shfl_xor(si2, off, 64);
            sr3 += __shfl_xor(sr3, off, 64); si3 += __shfl_xor(si3, off, 64);
        }
        if (lane == 0) {
            P[w][0] = sr0; P[w][1] = sr1; P[w][2] = sr2; P[w][3] = sr3;
            P[w][4] = si0; P[w][5] = si1; P[w][6] = si2; P[w][7] = si3;
        }
        __syncthreads();

        // ---- per-row ODE update (wave 0, threads 0..15) + publish ----
        if (tid < 16) {
            int g2 = tid >> 2, i = tid & 3;
            float u = P[2 * g2][i]     + P[2 * g2 + 1][i];      // Re(K z)
            float v = P[2 * g2][4 + i] + P[2 * g2 + 1][4 + i];  // Im(K z)
            int gr = bid * 16 + tid;
            float x = zr[gr], y = zi[gr];
            float A = x * x - y * y;           // Re(z^2)
            float B = 2.0f * x * y;            // Im(z^2)
            float dzr = inv2n * (u - (u * A + v * B)) + omega * x;
            float dzi = inv2n * (v - (u * B - v * A)) + omega * y;
            float nx = x + dt * dzr;
            float ny = y + dt * dzi;
            float a2 = nx * nx + ny * ny;
            if (a2 >= 0.999f * 0.999f) {
                float sc = 0.999f / sqrtf(a2);
                nx *= sc; ny *= sc;
            }
            if (s == NSTEPS - 1) {
                zfinal[gr] = make_float2(nx, ny);    // plain, untagged
            } else {
                union { float f; unsigned u; } cx, cy;
                cx.f = nx; cy.f = ny;
                cx.u = (cx.u & ~7u) | (unsigned)((s + 1) & 7);  // tag in x LSBs
                unsigned long long pk =
                    (unsigned long long)cx.u |
                    ((unsigned long long)cy.u << 32);
                float2* zo = ((s + 1) & 1) ? zb1 : zb0;
                zstore_u64(zo + gr, pk);             // fire-and-forget
            }
        }
        // no barrier — consumers self-gate on tags
    }
}

// ---- generic fallback: per-step launches ----
__global__ __launch_bounds__(256) void k_step_f32(
    const float* __restrict__ K, const float2* __restrict__ zin,
    float2* __restrict__ zout, const float* __restrict__ omega_p,
    const float* __restrict__ dt_p, int n) {
    const int wave = threadIdx.x >> 6;
    const int lane = threadIdx.x & 63;
    const int row  = blockIdx.x * 4 + wave;
    if (row >= n) return;
    float sr = 0.0f, si = 0.0f;
    for (int c = lane; c < n; c += 64) {
        float k = K[(size_t)row * n + c];
        float2 z = zin[c];
        sr += k * z.x;
        si += k * z.y;
    }
#pragma unroll
    for (int off = 32; off; off >>= 1) {
        sr += __shfl_down(sr, off, 64);
        si += __shfl_down(si, off, 64);
    }
    if (lane == 0) {
        float u = sr, v = si;
        float2 zc = zin[row];
        float x = zc.x, y = zc.y;
        float inv2n = 1.0f / (2.0f * n);
        float A = x * x - y * y, B = 2.0f * x * y;
        float dzr = inv2n * (u - (u * A + v * B)) + (*omega_p) * x;
        float dzi = inv2n * (v - (u * B - v * A)) + (*omega_p) * y;
        float nx = x + (*dt_p) * dzr, ny = y + (*dt_p) * dzi;
        float a2 = nx * nx + ny * ny;
        if (a2 >= 0.999f * 0.999f) { float sc = 0.999f / sqrtf(a2); nx *= sc; ny *= sc; }
        zout[row] = make_float2(nx, ny);
    }
}

extern "C" void kernel_launch(void* const* d_in, const int* in_sizes, int n_in,
                              void* d_out, int out_size, void* d_ws, size_t ws_size,
                              hipStream_t stream) {
    const float2* z0      = (const float2*)d_in[0];
    const float*  K       = (const float*)d_in[1];
    const float*  omega_p = (const float*)d_in[2];
    const float*  dt_p    = (const float*)d_in[3];
    const int n = in_sizes[0] / 2;
    float2* out = (float2*)d_out;

    const size_t need = 2 * (size_t)NN * sizeof(float2);   // two z buffers
    if (n == NN && ws_size >= need) {
        float2* zb0 = (float2*)d_ws;
        float2* zb1 = zb0 + NN;
        hipMemsetAsync(d_ws, 0, need, stream);   // tag 0 != any live tag (1,2)
        k_persist<<<NBLK, TPB, 0, stream>>>(K, z0, zb0, zb1, out,
                                            omega_p, dt_p);
    } else {
        float2* zb0 = (float2*)d_ws;
        float2* zb1 = zb0 + n;
        const float2* cur = z0;
        for (int s = 0; s < NSTEPS; ++s) {
            float2* nxt = (s == NSTEPS - 1) ? out : ((s & 1) ? zb1 : zb0);
            k_step_f32<<<(n + 3) / 4, 256, 0, stream>>>(K, cur, nxt, omega_p, dt_p, n);
            cur = nxt;
        }
    }
}